// Round 2
// baseline (1204.448 us; speedup 1.0000x reference)
//
#include <hip/hip_runtime.h>
#include <math.h>

// LambdaLayer fp32 baseline (round 2: fixed xf layout — reshape, not transpose).
// b=32 d=256 n=m=1024 k=16 h=4 v=64.
// xf[b,i,j] = x_flat[b, i*256+j]  (contiguous per-position feature rows).
// Reassociated position path: A[h,m] = sum_k q*E ; out[h,v] = sum_m A*vbn.
// 21.5 GFLOP total (vs 68.7 direct). fp32 vector-ALU bound.

#define BB 32
#define DD 256
#define NPOS 1024   // n == m
#define KDIM 16
#define HH 4
#define VV 64
#define F_EPS 1e-5f

#define NBLK 8      // n's per main block
#define TMM 64      // m-tile

// ---------------- K1: projections  xf[b,n,:] . W[c,:] -> out[b,c,n] -----------
// grid (B, 9, 4), block 256. ct 0: Wk->keys (16 rows); 1..4: Wv->vals; 5..8: Wq->qrs
// xf row n is the contiguous 256-float slice x[b, n*256 .. n*256+255].
__global__ void k_proj(const float* __restrict__ x,
                       const float* __restrict__ Wq,
                       const float* __restrict__ Wk,
                       const float* __restrict__ Wv,
                       float* __restrict__ keys,
                       float* __restrict__ vals,
                       float* __restrict__ qrs) {
    const int b = blockIdx.x, ct = blockIdx.y, nt = blockIdx.z;
    const int n = nt * 256 + threadIdx.x;
    const float* W; float* out;
    if (ct == 0)      { W = Wk;                    out = keys + b*KDIM*NPOS; }
    else if (ct < 5)  { W = Wv + (ct-1)*16*DD;     out = vals + b*VV*NPOS   + (ct-1)*16*NPOS; }
    else              { W = Wq + (ct-5)*16*DD;     out = qrs  + b*KDIM*HH*NPOS + (ct-5)*16*NPOS; }
    const float4* xr = (const float4*)(x + (size_t)b*DD*NPOS + (size_t)n*DD);
    float acc[16];
    #pragma unroll
    for (int c = 0; c < 16; ++c) acc[c] = 0.f;
    #pragma unroll 4
    for (int j4 = 0; j4 < DD/4; ++j4) {
        float4 xv = xr[j4];
        #pragma unroll
        for (int c = 0; c < 16; ++c) {          // W reads wave-uniform -> s_load
            acc[c] += W[c*DD + j4*4]     * xv.x
                    + W[c*DD + j4*4 + 1] * xv.y
                    + W[c*DD + j4*4 + 2] * xv.z
                    + W[c*DD + j4*4 + 3] * xv.w;
        }
    }
    #pragma unroll
    for (int c = 0; c < 16; ++c) out[c*NPOS + n] = acc[c];
}

// ---------------- K: zero stats ----------------
__global__ void k_zero(float* __restrict__ p, int nfl) {
    int i = blockIdx.x * 256 + threadIdx.x;
    if (i < nfl) p[i] = 0.f;
}

// ---------------- K2a: softmax over m for each (b,kd), in place -------------
// 512 rows of 1024; one wave per row. grid 128, block 256.
__global__ void k_softmax(float* __restrict__ keys) {
    const int wid  = (blockIdx.x * 256 + threadIdx.x) >> 6;  // 0..511
    const int lane = threadIdx.x & 63;
    float* row = keys + (size_t)wid * NPOS;
    float v[16];
    float mx = -1e30f;
    #pragma unroll
    for (int j = 0; j < 16; ++j) { v[j] = row[lane + 64*j]; mx = fmaxf(mx, v[j]); }
    #pragma unroll
    for (int off = 32; off >= 1; off >>= 1) mx = fmaxf(mx, __shfl_xor(mx, off));
    float s = 0.f;
    #pragma unroll
    for (int j = 0; j < 16; ++j) { v[j] = __expf(v[j] - mx); s += v[j]; }
    #pragma unroll
    for (int off = 32; off >= 1; off >>= 1) s += __shfl_xor(s, off);
    float inv = 1.f / s;
    #pragma unroll
    for (int j = 0; j < 16; ++j) row[lane + 64*j] = v[j] * inv;
}

// ---------------- K2b: value BN stats (sum, sumsq per m over b,v) -----------
// grid 64, block 256. sv[0..1023]=sum, sv[1024..2047]=sumsq
__global__ void k_vstats(const float* __restrict__ vals, float* __restrict__ sv) {
    const int g = blockIdx.x, t = threadIdx.x;
    float s[4] = {0,0,0,0}, q[4] = {0,0,0,0};
    for (int r = g*32; r < g*32 + 32; ++r) {
        const float* row = vals + (size_t)r * NPOS;
        #pragma unroll
        for (int j = 0; j < 4; ++j) { float x = row[t + 256*j]; s[j] += x; q[j] += x*x; }
    }
    #pragma unroll
    for (int j = 0; j < 4; ++j) {
        atomicAdd(&sv[t + 256*j], s[j]);
        atomicAdd(&sv[1024 + t + 256*j], q[j]);
    }
}

// sv -> scale/shift. grid 4, block 256.
__global__ void k_vfinal(float* __restrict__ sv, const float* __restrict__ gv,
                         const float* __restrict__ bv) {
    int m = blockIdx.x*256 + threadIdx.x;
    float mean = sv[m] * (1.f/2048.f);
    float var  = sv[1024+m] * (1.f/2048.f) - mean*mean;
    float sc = rsqrtf(var + F_EPS) * gv[m];
    sv[m] = sc;
    sv[1024+m] = bv[m] - mean*sc;
}

// apply BN to vals in place, float4. grid 2048, block 256.
__global__ void k_vapply(float* __restrict__ vals, const float* __restrict__ sv) {
    int i = blockIdx.x*256 + threadIdx.x;
    int m = (i & 255) * 4;
    float4 x = ((float4*)vals)[i];
    x.x = x.x*sv[m]   + sv[1024+m];
    x.y = x.y*sv[m+1] + sv[1025+m];
    x.z = x.z*sv[m+2] + sv[1026+m];
    x.w = x.w*sv[m+3] + sv[1027+m];
    ((float4*)vals)[i] = x;
}

// ---------------- K2d: query BN stats (per kd over b,n,h) -------------------
// grid 128 (kd*8+sub), block 256. sq[0..15]=sum, sq[16..31]=sumsq
__global__ void k_qstats(const float* __restrict__ qrs, float* __restrict__ sq) {
    const int kd = blockIdx.x >> 3, sub = blockIdx.x & 7;
    float s = 0.f, ss = 0.f;
    for (int b = sub*4; b < sub*4 + 4; ++b)
        for (int h = 0; h < HH; ++h) {
            const float* row = qrs + ((size_t)(b*KDIM*HH) + kd*4 + h) * NPOS;
            #pragma unroll
            for (int j = 0; j < 4; ++j) { float x = row[threadIdx.x + 256*j]; s += x; ss += x*x; }
        }
    #pragma unroll
    for (int off = 32; off >= 1; off >>= 1) { s += __shfl_xor(s, off); ss += __shfl_xor(ss, off); }
    __shared__ float red[8];
    int w = threadIdx.x >> 6, lane = threadIdx.x & 63;
    if (lane == 0) { red[w] = s; red[4+w] = ss; }
    __syncthreads();
    if (threadIdx.x == 0) atomicAdd(&sq[kd],      red[0]+red[1]+red[2]+red[3]);
    if (threadIdx.x == 1) atomicAdd(&sq[16+kd],   red[4]+red[5]+red[6]+red[7]);
}

// grid 1, block 16
__global__ void k_qfinal(float* __restrict__ sq, const float* __restrict__ gq,
                         const float* __restrict__ bq) {
    int kd = threadIdx.x;
    const float inv = 1.f / 131072.f;   // b*n*h
    float mean = sq[kd] * inv;
    float var  = sq[16+kd] * inv - mean*mean;
    float sc = rsqrtf(var + F_EPS) * gq[kd];
    sq[kd] = sc;
    sq[16+kd] = bq[kd] - mean*sc;
}

// apply BN to qrs in place. grid 2048, block 256.
__global__ void k_qapply(float* __restrict__ qrs, const float* __restrict__ sq) {
    int i = blockIdx.x*256 + threadIdx.x;
    int kd = ((i >> 8) & 63) >> 2;       // row c = kd*4+h, rows are 1024 floats = 256 f4
    float sc = sq[kd], sh = sq[16+kd];
    float4 x = ((float4*)qrs)[i];
    x.x = x.x*sc + sh; x.y = x.y*sc + sh; x.z = x.z*sc + sh; x.w = x.w*sc + sh;
    ((float4*)qrs)[i] = x;
}

// ---------------- K3: content_lambda[b,kd,v] = sum_m sk*vbn ----------------
// grid 512 (b*16+kd), block 256
__global__ void k_cl(const float* __restrict__ sk, const float* __restrict__ vals,
                     float* __restrict__ cl) {
    const int b = blockIdx.x >> 4, kd = blockIdx.x & 15;
    __shared__ float skl[NPOS];
    __shared__ float red[256];
    const float* srow = sk + ((size_t)b*KDIM + kd) * NPOS;
    #pragma unroll
    for (int j = 0; j < 4; ++j) skl[threadIdx.x + 256*j] = srow[threadIdx.x + 256*j];
    __syncthreads();
    const int v = threadIdx.x >> 2, q = threadIdx.x & 3;
    const float4* v4 = (const float4*)(vals + ((size_t)b*VV + v) * NPOS + q*256);
    const float4* s4 = (const float4*)(skl + q*256);
    float s = 0.f;
    #pragma unroll 8
    for (int m = 0; m < 64; ++m) {
        float4 a = s4[m], c = v4[m];
        s += a.x*c.x + a.y*c.y + a.z*c.z + a.w*c.w;
    }
    red[threadIdx.x] = s;
    __syncthreads();
    if ((threadIdx.x & 3) == 0) {
        float r = red[threadIdx.x] + red[threadIdx.x+1] + red[threadIdx.x+2] + red[threadIdx.x+3];
        cl[((size_t)b*KDIM + kd)*VV + v] = r;
    }
}

// ---------------- K4: main fused position+content kernel -------------------
// grid (32 b, 128 ngroups of NBLK n), block 256. b fastest -> E tile reuse in L2/L3.
__global__ __launch_bounds__(256, 2) void k_main(
        const float* __restrict__ qrs, const float* __restrict__ vals,
        const float* __restrict__ E, const float* __restrict__ cl,
        float* __restrict__ out) {
    __shared__ float E_lds[NBLK][TMM][20];   // pad 16->20 (40 KB)
    __shared__ float A_lds[NBLK][HH][68];    // pad 64->68 (8.7 KB)
    __shared__ float vb_lds[VV][68];         // pad 64->68 (17.4 KB)
    __shared__ float q_lds[NBLK][64];
    __shared__ float cl_lds[KDIM][VV];

    const int b  = blockIdx.x;
    const int n0 = blockIdx.y * NBLK;
    const int t  = threadIdx.x;

    { // queries for this n-group: q_lds[nn][c], c = kd*4+h
        int c = t & 63, nn = t >> 6;
        q_lds[nn][c]     = qrs[((size_t)b*64 + c)*NPOS + n0 + nn];
        q_lds[nn + 4][c] = qrs[((size_t)b*64 + c)*NPOS + n0 + nn + 4];
    }
    { // content lambda for this b
        int kd = t >> 6, v = t & 63;
        #pragma unroll
        for (int j = 0; j < 4; ++j)
            cl_lds[kd + 4*j][v] = cl[((size_t)b*KDIM + kd + 4*j)*VV + v];
    }
    __syncthreads();

    // A-step mapping: t -> (nn, h, ms)
    const int a_nn = t >> 5, a_h = (t >> 3) & 3, a_ms = t & 7;
    float qreg[KDIM];
    #pragma unroll
    for (int k = 0; k < KDIM; ++k) qreg[k] = q_lds[a_nn][k*4 + a_h];

    // B-step mapping: t -> (h, vg, nh); v in {vg, vg+32}, nn in nh*4..+3
    const int h = t & 3, vg = (t >> 2) & 31, nh = t >> 7;

    float acc[2][4] = {{0,0,0,0},{0,0,0,0}};
    const float* vb_src = vals + (size_t)b*VV*NPOS;

    for (int mt = 0; mt < NPOS/TMM; ++mt) {
        const int m0 = mt * TMM;
        __syncthreads();  // previous B-step readers done before overwrite
        { // E tile: per j one n, fully coalesced 4KB
            int mi = t >> 2, k4 = t & 3;
            #pragma unroll
            for (int j = 0; j < NBLK; ++j) {
                float4 e = *(const float4*)(E + ((size_t)(n0+j)*NPOS + m0 + mi)*KDIM + k4*4);
                *(float4*)&E_lds[j][mi][k4*4] = e;
            }
        }
        { // vbn tile
            int mc = t & 15, vvi = t >> 4;
            #pragma unroll
            for (int j = 0; j < 4; ++j) {
                float4 w = *(const float4*)(vb_src + (size_t)(vvi + 16*j)*NPOS + m0 + mc*4);
                *(float4*)&vb_lds[vvi + 16*j][mc*4] = w;
            }
        }
        __syncthreads();
        // A-step: A[nn][h][m] = sum_k q * E
        #pragma unroll
        for (int i = 0; i < 8; ++i) {
            int m = a_ms + 8*i;
            const float4* er = (const float4*)&E_lds[a_nn][m][0];
            float4 e0 = er[0], e1 = er[1], e2 = er[2], e3 = er[3];
            float a = qreg[0]*e0.x + qreg[1]*e0.y + qreg[2]*e0.z + qreg[3]*e0.w
                    + qreg[4]*e1.x + qreg[5]*e1.y + qreg[6]*e1.z + qreg[7]*e1.w
                    + qreg[8]*e2.x + qreg[9]*e2.y + qreg[10]*e2.z + qreg[11]*e2.w
                    + qreg[12]*e3.x + qreg[13]*e3.y + qreg[14]*e3.z + qreg[15]*e3.w;
            A_lds[a_nn][a_h][m] = a;
        }
        __syncthreads();
        // B-step: acc[vi][j] += A[nn][h][m] * vbn[v][m]
        #pragma unroll
        for (int mi = 0; mi < TMM/4; ++mi) {
            float4 vb0 = *(const float4*)&vb_lds[vg][mi*4];
            float4 vb1 = *(const float4*)&vb_lds[vg + 32][mi*4];
            #pragma unroll
            for (int j = 0; j < 4; ++j) {
                float4 a4 = *(const float4*)&A_lds[nh*4 + j][h][mi*4];
                acc[0][j] += a4.x*vb0.x + a4.y*vb0.y + a4.z*vb0.z + a4.w*vb0.w;
                acc[1][j] += a4.x*vb1.x + a4.y*vb1.y + a4.z*vb1.z + a4.w*vb1.w;
            }
        }
    }

    // epilogue: + content, store (float4 over 4 consecutive n)
    #pragma unroll
    for (int vi = 0; vi < 2; ++vi) {
        int v = vg + 32*vi;
        float r[4];
        #pragma unroll
        for (int j = 0; j < 4; ++j) {
            int nn = nh*4 + j;
            float c = 0.f;
            #pragma unroll
            for (int k = 0; k < KDIM; ++k) c += q_lds[nn][k*4 + h] * cl_lds[k][v];
            r[j] = acc[vi][j] + c;
        }
        *(float4*)(out + (((size_t)b*HH + h)*VV + v)*NPOS + n0 + nh*4)
            = make_float4(r[0], r[1], r[2], r[3]);
    }
}

// ---------------- launch -------------------
extern "C" void kernel_launch(void* const* d_in, const int* in_sizes, int n_in,
                              void* d_out, int out_size, void* d_ws, size_t ws_size,
                              hipStream_t stream) {
    const float* x  = (const float*)d_in[0];
    const float* Wq = (const float*)d_in[1];
    const float* Wk = (const float*)d_in[2];
    const float* Wv = (const float*)d_in[3];
    const float* E  = (const float*)d_in[4];
    const float* gv = (const float*)d_in[5];
    const float* bv = (const float*)d_in[6];
    const float* gq = (const float*)d_in[7];
    const float* bq = (const float*)d_in[8];
    float* out = (float*)d_out;

    float* ws   = (float*)d_ws;
    float* keys = ws;                          // 32*16*1024   = 524288   (-> softmax_keys)
    float* vals = keys + 524288;               // 32*64*1024   = 2097152  (-> BN'd values)
    float* qrs  = vals + 2097152;              // 32*64*1024   = 2097152  (-> BN'd queries)
    float* cl   = qrs  + 2097152;              // 32*16*64     = 32768
    float* sv   = cl   + 32768;                // 2048
    float* sq   = sv   + 2048;                 // 32
    // total ~18.2 MB of d_ws

    k_zero<<<9, 256, 0, stream>>>(sv, 2048 + 32);
    k_proj<<<dim3(BB, 9, 4), 256, 0, stream>>>(x, Wq, Wk, Wv, keys, vals, qrs);
    k_softmax<<<128, 256, 0, stream>>>(keys);
    k_vstats<<<64, 256, 0, stream>>>(vals, sv);
    k_vfinal<<<4, 256, 0, stream>>>(sv, gv, bv);
    k_vapply<<<2048, 256, 0, stream>>>(vals, sv);
    k_qstats<<<128, 256, 0, stream>>>(qrs, sq);
    k_qfinal<<<1, 16, 0, stream>>>(sq, gq, bq);
    k_qapply<<<2048, 256, 0, stream>>>(qrs, sq);
    k_cl<<<512, 256, 0, stream>>>(keys, vals, cl);
    k_main<<<dim3(BB, NPOS/NBLK), 256, 0, stream>>>(qrs, vals, E, cl, out);
}

// Round 3
// 508.159 us; speedup vs baseline: 2.3702x; 2.3702x over previous
//
#include <hip/hip_runtime.h>
#include <math.h>

// LambdaLayer round 3: bf16 MFMA main kernel.
// b=32 d=256 n=m=1024 k=16 h=4 v=64.
// A-step: A[m,h] = sum_k E[n,m,k]*q[k,n,h]   (MFMA 16x16x32, K padded: q rows 16-31 = 0)
// B-step: out[(nn,h),v] = sum_m A*vbn        (MFMA 16x16x32, 2x2 wave split)
// content term = one extra virtual K-step (A-op = q rows, B-op = cl rows), operands from global.

#define BB 32
#define DD 256
#define NPOS 1024
#define KDIM 16
#define HH 4
#define VV 64
#define F_EPS 1e-5f

#define NBLK 8
#define TMM 64

typedef __attribute__((ext_vector_type(8))) short short8;   // 8 bf16 (4 VGPR)
typedef __attribute__((ext_vector_type(4))) float f32x4;
typedef unsigned short ushort_t;
typedef unsigned int uint_t;

typedef __attribute__((address_space(1))) const uint_t g32_t;
typedef __attribute__((address_space(3))) uint_t l32_t;

__device__ __forceinline__ void gload16(const void* g, void* l) {
    __builtin_amdgcn_global_load_lds((g32_t*)g, (l32_t*)l, 16, 0, 0);
}

__device__ __forceinline__ uint_t bfpack(float x, float y) {   // 2 f32 -> packed bf16 pair (RNE)
    uint_t ux = __float_as_uint(x), uy = __float_as_uint(y);
    ux = (ux + 0x7FFFu + ((ux >> 16) & 1u)) >> 16;
    uy = (uy + 0x7FFFu + ((uy >> 16) & 1u)) >> 16;
    return ux | (uy << 16);
}
__device__ __forceinline__ ushort_t f2bf(float x) {
    uint_t u = __float_as_uint(x);
    return (ushort_t)((u + 0x7FFFu + ((u >> 16) & 1u)) >> 16);
}
__device__ __forceinline__ float bflo(uint_t u) { return __uint_as_float(u << 16); }
__device__ __forceinline__ float bfhi(uint_t u) { return __uint_as_float(u & 0xFFFF0000u); }

// ---------------- K1: projections (unchanged fp32) -------------
__global__ void k_proj(const float* __restrict__ x,
                       const float* __restrict__ Wq,
                       const float* __restrict__ Wk,
                       const float* __restrict__ Wv,
                       float* __restrict__ keys,
                       float* __restrict__ vals,
                       float* __restrict__ qrs) {
    const int b = blockIdx.x, ct = blockIdx.y, nt = blockIdx.z;
    const int n = nt * 256 + threadIdx.x;
    const float* W; float* out;
    if (ct == 0)      { W = Wk;                    out = keys + b*KDIM*NPOS; }
    else if (ct < 5)  { W = Wv + (ct-1)*16*DD;     out = vals + b*VV*NPOS   + (ct-1)*16*NPOS; }
    else              { W = Wq + (ct-5)*16*DD;     out = qrs  + b*KDIM*HH*NPOS + (ct-5)*16*NPOS; }
    const float4* xr = (const float4*)(x + (size_t)b*DD*NPOS + (size_t)n*DD);
    float acc[16];
    #pragma unroll
    for (int c = 0; c < 16; ++c) acc[c] = 0.f;
    #pragma unroll 4
    for (int j4 = 0; j4 < DD/4; ++j4) {
        float4 xv = xr[j4];
        #pragma unroll
        for (int c = 0; c < 16; ++c) {
            acc[c] += W[c*DD + j4*4]     * xv.x
                    + W[c*DD + j4*4 + 1] * xv.y
                    + W[c*DD + j4*4 + 2] * xv.z
                    + W[c*DD + j4*4 + 3] * xv.w;
        }
    }
    #pragma unroll
    for (int c = 0; c < 16; ++c) out[c*NPOS + n] = acc[c];
}

__global__ void k_zero(float* __restrict__ p, int nfl) {
    int i = blockIdx.x * 256 + threadIdx.x;
    if (i < nfl) p[i] = 0.f;
}

// ---------------- E f32 -> bf16 ----------------
__global__ void k_ecvt(const float* __restrict__ E, ushort_t* __restrict__ Eb) {
    size_t i = (size_t)blockIdx.x * 256 + threadIdx.x;   // x8 elems
    const float4* s = (const float4*)(E + i*8);
    float4 a = s[0], c = s[1];
    uint4 o;
    o.x = bfpack(a.x, a.y); o.y = bfpack(a.z, a.w);
    o.z = bfpack(c.x, c.y); o.w = bfpack(c.z, c.w);
    *(uint4*)(Eb + i*8) = o;
}

// ---------------- softmax (unchanged) ----------------
__global__ void k_softmax(float* __restrict__ keys) {
    const int wid  = (blockIdx.x * 256 + threadIdx.x) >> 6;
    const int lane = threadIdx.x & 63;
    float* row = keys + (size_t)wid * NPOS;
    float v[16];
    float mx = -1e30f;
    #pragma unroll
    for (int j = 0; j < 16; ++j) { v[j] = row[lane + 64*j]; mx = fmaxf(mx, v[j]); }
    #pragma unroll
    for (int off = 32; off >= 1; off >>= 1) mx = fmaxf(mx, __shfl_xor(mx, off));
    float s = 0.f;
    #pragma unroll
    for (int j = 0; j < 16; ++j) { v[j] = __expf(v[j] - mx); s += v[j]; }
    #pragma unroll
    for (int off = 32; off >= 1; off >>= 1) s += __shfl_xor(s, off);
    float inv = 1.f / s;
    #pragma unroll
    for (int j = 0; j < 16; ++j) row[lane + 64*j] = v[j] * inv;
}

// ---------------- value BN stats (unchanged) ----------------
__global__ void k_vstats(const float* __restrict__ vals, float* __restrict__ sv) {
    const int g = blockIdx.x, t = threadIdx.x;
    float s[4] = {0,0,0,0}, q[4] = {0,0,0,0};
    for (int r = g*32; r < g*32 + 32; ++r) {
        const float* row = vals + (size_t)r * NPOS;
        #pragma unroll
        for (int j = 0; j < 4; ++j) { float x = row[t + 256*j]; s[j] += x; q[j] += x*x; }
    }
    #pragma unroll
    for (int j = 0; j < 4; ++j) {
        atomicAdd(&sv[t + 256*j], s[j]);
        atomicAdd(&sv[1024 + t + 256*j], q[j]);
    }
}

__global__ void k_vfinal(float* __restrict__ sv, const float* __restrict__ gv,
                         const float* __restrict__ bv) {
    int m = blockIdx.x*256 + threadIdx.x;
    float mean = sv[m] * (1.f/2048.f);
    float var  = sv[1024+m] * (1.f/2048.f) - mean*mean;
    float sc = rsqrtf(var + F_EPS) * gv[m];
    sv[m] = sc;
    sv[1024+m] = bv[m] - mean*sc;
}

// ---------------- BN-apply + cvt: vals f32 -> vb_bf16 [b][v][m] ----------------
__global__ void k_vcvt(const float* __restrict__ vals, const float* __restrict__ sv,
                       ushort_t* __restrict__ vb) {
    int i = blockIdx.x*256 + threadIdx.x;       // x8 elems
    int m0 = (i & 127) * 8;
    const float4* src = (const float4*)(vals + (size_t)i*8);
    float4 a = src[0], c = src[1];
    float4 s0 = *(const float4*)(sv + m0),        s1 = *(const float4*)(sv + m0 + 4);
    float4 h0 = *(const float4*)(sv + 1024 + m0), h1 = *(const float4*)(sv + 1024 + m0 + 4);
    a.x = a.x*s0.x + h0.x; a.y = a.y*s0.y + h0.y; a.z = a.z*s0.z + h0.z; a.w = a.w*s0.w + h0.w;
    c.x = c.x*s1.x + h1.x; c.y = c.y*s1.y + h1.y; c.z = c.z*s1.z + h1.z; c.w = c.w*s1.w + h1.w;
    uint4 o;
    o.x = bfpack(a.x, a.y); o.y = bfpack(a.z, a.w);
    o.z = bfpack(c.x, c.y); o.w = bfpack(c.z, c.w);
    *(uint4*)(vb + (size_t)i*8) = o;
}

// ---------------- query BN stats (unchanged) ----------------
__global__ void k_qstats(const float* __restrict__ qrs, float* __restrict__ sq) {
    const int kd = blockIdx.x >> 3, sub = blockIdx.x & 7;
    float s = 0.f, ss = 0.f;
    for (int b = sub*4; b < sub*4 + 4; ++b)
        for (int h = 0; h < HH; ++h) {
            const float* row = qrs + ((size_t)(b*KDIM*HH) + kd*4 + h) * NPOS;
            #pragma unroll
            for (int j = 0; j < 4; ++j) { float x = row[threadIdx.x + 256*j]; s += x; ss += x*x; }
        }
    #pragma unroll
    for (int off = 32; off >= 1; off >>= 1) { s += __shfl_xor(s, off); ss += __shfl_xor(ss, off); }
    __shared__ float red[8];
    int w = threadIdx.x >> 6, lane = threadIdx.x & 63;
    if (lane == 0) { red[w] = s; red[4+w] = ss; }
    __syncthreads();
    if (threadIdx.x == 0) atomicAdd(&sq[kd],    red[0]+red[1]+red[2]+red[3]);
    if (threadIdx.x == 1) atomicAdd(&sq[16+kd], red[4]+red[5]+red[6]+red[7]);
}

__global__ void k_qfinal(float* __restrict__ sq, const float* __restrict__ gq,
                         const float* __restrict__ bq) {
    int kd = threadIdx.x;
    const float inv = 1.f / 131072.f;
    float mean = sq[kd] * inv;
    float var  = sq[16+kd] * inv - mean*mean;
    float sc = rsqrtf(var + F_EPS) * gq[kd];
    sq[kd] = sc;
    sq[16+kd] = bq[kd] - mean*sc;
}

// ---------------- BN-apply + transpose: qrs[b][kd*4+h][n] -> q_bf16[b][n*4+h][32k] ---
// k 16..31 zeroed (MFMA K-pad). grid (32b x 16 ntiles), block 256.
__global__ void k_qT(const float* __restrict__ qrs, const float* __restrict__ sq,
                     ushort_t* __restrict__ qb) {
    __shared__ float tile[64][68];
    const int b = blockIdx.x >> 4, n0 = (blockIdx.x & 15) * 64;
    const int t = threadIdx.x;
    {
        int c = t >> 2, j0 = t & 3;
        const float4* src = (const float4*)(qrs + ((size_t)b*64 + c)*NPOS + n0);
        #pragma unroll
        for (int i = 0; i < 4; ++i) {
            float4 v = src[j0 + i*4];
            *(float4*)&tile[c][(j0 + i*4)*4] = v;
        }
    }
    __syncthreads();
    int n_l = t >> 2, h = t & 3;
    float q16[16];
    #pragma unroll
    for (int kd = 0; kd < 16; ++kd)
        q16[kd] = tile[kd*4 + h][n_l] * sq[kd] + sq[16 + kd];
    uint4 lo, hi, z;
    lo.x = bfpack(q16[0], q16[1]);  lo.y = bfpack(q16[2], q16[3]);
    lo.z = bfpack(q16[4], q16[5]);  lo.w = bfpack(q16[6], q16[7]);
    hi.x = bfpack(q16[8], q16[9]);  hi.y = bfpack(q16[10], q16[11]);
    hi.z = bfpack(q16[12], q16[13]); hi.w = bfpack(q16[14], q16[15]);
    z.x = z.y = z.z = z.w = 0u;
    ushort_t* dst = qb + (size_t)b*131072 + (size_t)((n0 + n_l)*4 + h)*32;
    *(uint4*)(dst)      = lo;
    *(uint4*)(dst + 8)  = hi;
    *(uint4*)(dst + 16) = z;
    *(uint4*)(dst + 24) = z;
}

// ---------------- content lambda -> cl_bf16[b][v][16kd] ----------------
__global__ void k_cl(const float* __restrict__ sk, const ushort_t* __restrict__ vb,
                     ushort_t* __restrict__ clb) {
    const int b = blockIdx.x >> 4, kd = blockIdx.x & 15;
    __shared__ float skl[NPOS];
    __shared__ float red[256];
    const int t = threadIdx.x;
    const float* srow = sk + ((size_t)b*KDIM + kd) * NPOS;
    #pragma unroll
    for (int j = 0; j < 4; ++j) skl[t + 256*j] = srow[t + 256*j];
    __syncthreads();
    const int v = t >> 2, q = t & 3;
    const uint4* v4 = (const uint4*)(vb + ((size_t)b*VV + v) * NPOS + q*256);
    const float4* s4 = (const float4*)(skl + q*256);
    float s = 0.f;
    #pragma unroll 8
    for (int m8 = 0; m8 < 32; ++m8) {
        uint4 wv = v4[m8];
        float4 sa = s4[m8*2], sb = s4[m8*2+1];
        s += sa.x*bflo(wv.x) + sa.y*bfhi(wv.x) + sa.z*bflo(wv.y) + sa.w*bfhi(wv.y)
           + sb.x*bflo(wv.z) + sb.y*bfhi(wv.z) + sb.z*bflo(wv.w) + sb.w*bfhi(wv.w);
    }
    red[t] = s;
    __syncthreads();
    if (q == 0) {
        float r = red[t] + red[t+1] + red[t+2] + red[t+3];
        clb[((size_t)b*VV + v)*16 + kd] = f2bf(r);
    }
}

// ---------------- K4: MFMA main kernel ----------------
// grid 4096 = (8 xcd) x (32 b) x (16 glocal); block 256 = 4 waves.
__global__ __launch_bounds__(256) void k_main(
        const ushort_t* __restrict__ qb, const ushort_t* __restrict__ vb,
        const ushort_t* __restrict__ Eb, const ushort_t* __restrict__ clb,
        float* __restrict__ out) {
    __shared__ ushort_t E_lds[2][NBLK][TMM][16];   // 32 KB, linear (DMA)
    __shared__ ushort_t vb_lds[2][VV][TMM];        // 16 KB, XOR-swizzled
    __shared__ ushort_t A_lds[32][TMM];            // 4 KB,  XOR-swizzled

    const int wg  = blockIdx.x;
    const int b   = (wg >> 3) & 31;
    const int g   = (wg & 7) * 16 + (wg >> 8);     // XCD-resident E tiles
    const int n0  = g * NBLK;
    const int t   = threadIdx.x;
    const int w   = t >> 6, lane = t & 63;
    const int l15 = lane & 15, l4 = lane >> 4;

    char* Ab = (char*)&A_lds[0][0];

    // ---- per-wave B-step roles
    const int mw = w & 1, vf0 = (w >> 1) * 2;

    // ---- prologue: q fragments for A-step (this wave's two n's)
    short8 qf[2];
    #pragma unroll
    for (int j = 0; j < 2; ++j) {
        const ushort_t* qp = qb + ((size_t)b*131072)
                           + (size_t)((n0 + w*2 + j)*4 + l15)*32 + l4*8;
        qf[j] = *(const short8*)qp;                 // lanes>=32 hit the zero pad (K 16-31)
    }

    // ---- staging helpers
    const ushort_t* vb_b = vb + (size_t)b*VV*NPOS;

    #define STAGE(mt, bufi) do {                                                  \
        const int m0_ = (mt) * TMM;                                               \
        _Pragma("unroll")                                                         \
        for (int qq = 0; qq < 4; ++qq) {                                          \
            int flat = w*4 + qq, nn_ = flat >> 1, half_ = flat & 1;               \
            const ushort_t* src = Eb + ((size_t)(n0+nn_)*NPOS + m0_)*16           \
                                   + half_*512 + lane*8;                          \
            gload16(src, &E_lds[bufi][nn_][half_*32][0]);                         \
        }                                                                         \
        _Pragma("unroll")                                                         \
        for (int qq = 0; qq < 2; ++qq) {                                          \
            int slot = (w*2 + qq)*64 + lane;                                      \
            int v_ = slot >> 3, cs_ = slot & 7, c_ = cs_ ^ (v_ & 7);              \
            const ushort_t* src = vb_b + (size_t)v_*NPOS + m0_ + c_*8;            \
            gload16(src, (char*)&vb_lds[bufi][0][0] + (w*2 + qq)*1024);           \
        }                                                                         \
    } while (0)

    STAGE(0, 0);
    asm volatile("s_waitcnt vmcnt(0)" ::: "memory");
    __syncthreads();

    f32x4 acc[2];
    acc[0] = (f32x4){0.f,0.f,0.f,0.f};
    acc[1] = (f32x4){0.f,0.f,0.f,0.f};

    int buf = 0;
    for (int mt = 0; mt < NPOS/TMM; ++mt) {
        if (mt < NPOS/TMM - 1) STAGE(mt + 1, buf ^ 1);

        // ---- A-step: 8 MFMAs (2 n x 4 m-frags), read E_lds[buf]
        f32x4 aacc[8];
        #pragma unroll
        for (int j = 0; j < 2; ++j) {
            #pragma unroll
            for (int mf = 0; mf < 4; ++mf) {
                short8 e = *(const short8*)&E_lds[buf][w*2 + j][mf*16 + l15][(l4 & 1)*8];
                aacc[j*4 + mf] = __builtin_amdgcn_mfma_f32_16x16x32_bf16(
                    e, qf[j], (f32x4){0.f,0.f,0.f,0.f}, 0, 0, 0);
            }
        }
        __syncthreads();   // prev B-step readers of A_lds done

        // ---- write A (16 active lanes per frag), swizzled
        if (l15 < 4) {
            #pragma unroll
            for (int j = 0; j < 2; ++j) {
                int arow = (w*2 + j)*4 + l15;
                int sw = (arow & 7) << 4;
                #pragma unroll
                for (int mf = 0; mf < 4; ++mf) {
                    f32x4 a = aacc[j*4 + mf];
                    int byte = (arow*128 + mf*32 + l4*8) ^ sw;
                    *(uint2*)(Ab + byte) = make_uint2(bfpack(a[0], a[1]), bfpack(a[2], a[3]));
                }
            }
        }
        __syncthreads();   // A visible; vb[buf] ready since prev iter

        // ---- B-step: 4 MFMAs (1 M-frag x 2 N-frags x 2 K-steps)
        #pragma unroll
        for (int s = 0; s < 2; ++s) {
            int arow = mw*16 + l15;
            int abyte = (arow*128 + s*64 + l4*16) ^ ((arow & 7) << 4);
            short8 af = *(const short8*)(Ab + abyte);
            #pragma unroll
            for (int nf = 0; nf < 2; ++nf) {
                int v_ = (vf0 + nf)*16 + l15;
                int vbyte = (v_*128 + (s*4 + l4)*16) ^ ((v_ & 7) << 4);
                short8 bfr = *(const short8*)((char*)&vb_lds[buf][0][0] + vbyte);
                acc[nf] = __builtin_amdgcn_mfma_f32_16x16x32_bf16(af, bfr, acc[nf], 0, 0, 0);
            }
        }

        asm volatile("s_waitcnt vmcnt(0)" ::: "memory");
        __syncthreads();   // next-tile buffers ready for all waves
        buf ^= 1;
    }

    // ---- virtual K-step: content term (operands straight from global, L2-hot)
    {
        const ushort_t* qa = qb + (size_t)b*131072
                           + (size_t)(n0*4 + mw*16 + l15)*32 + l4*8;
        short8 aq = *(const short8*)qa;   // k16-31 zeros
        #pragma unroll
        for (int nf = 0; nf < 2; ++nf) {
            const ushort_t* cb = clb + ((size_t)b*VV + (vf0 + nf)*16 + l15)*16 + l4*8;
            short8 bq = *(const short8*)cb;   // k>=16 overrun harmless (A side zero)
            acc[nf] = __builtin_amdgcn_mfma_f32_16x16x32_bf16(aq, bq, acc[nf], 0, 0, 0);
        }
    }

    // ---- store: C row r = nn*4+h, col = v
    #pragma unroll
    for (int nf = 0; nf < 2; ++nf) {
        int v_ = (vf0 + nf)*16 + l15;
        int r0 = mw*16 + l4*4;
        int nn = r0 >> 2;
        #pragma unroll
        for (int i = 0; i < 4; ++i) {
            out[(((size_t)b*HH + i)*VV + v_)*NPOS + n0 + nn] = acc[nf][i];
        }
    }
    #undef STAGE
}

// ---------------- launch -------------------
extern "C" void kernel_launch(void* const* d_in, const int* in_sizes, int n_in,
                              void* d_out, int out_size, void* d_ws, size_t ws_size,
                              hipStream_t stream) {
    const float* x  = (const float*)d_in[0];
    const float* Wq = (const float*)d_in[1];
    const float* Wk = (const float*)d_in[2];
    const float* Wv = (const float*)d_in[3];
    const float* E  = (const float*)d_in[4];
    const float* gv = (const float*)d_in[5];
    const float* bv = (const float*)d_in[6];
    const float* gq = (const float*)d_in[7];
    const float* bq = (const float*)d_in[8];
    float* out = (float*)d_out;

    float* ws   = (float*)d_ws;
    float* keys = ws;                          // 524288 f32
    float* vals = keys + 524288;               // 2097152 f32
    float* qrs  = vals + 2097152;              // 2097152 f32
    float* sv   = qrs  + 2097152;              // 2048
    float* sq   = sv   + 2048;                 // 32
    ushort_t* cl_bf = (ushort_t*)(sq + 32);    // 32768 + 64 pad u16   (16416 f32)
    ushort_t* q_bf  = cl_bf + 32832;           // 4194304 + 2048 pad u16 (2098176 f32)
    ushort_t* vb_bf = q_bf  + 4196352;         // 2097152 u16 (1048576 f32)
    ushort_t* E_bf  = vb_bf + 2097152;         // 16777216 u16 (8388608 f32)
    // total ~65 MB of d_ws

    k_zero<<<9, 256, 0, stream>>>(sv, 2048 + 32);
    k_proj<<<dim3(BB, 9, 4), 256, 0, stream>>>(x, Wq, Wk, Wv, keys, vals, qrs);
    k_ecvt<<<8192, 256, 0, stream>>>(E, E_bf);
    k_softmax<<<128, 256, 0, stream>>>(keys);
    k_vstats<<<64, 256, 0, stream>>>(vals, sv);
    k_vfinal<<<4, 256, 0, stream>>>(sv, gv, bv);
    k_vcvt<<<1024, 256, 0, stream>>>(vals, sv, vb_bf);
    k_qstats<<<128, 256, 0, stream>>>(qrs, sq);
    k_qfinal<<<1, 16, 0, stream>>>(sq, gq, bq);
    k_qT<<<512, 256, 0, stream>>>(qrs, sq, q_bf);
    k_cl<<<512, 256, 0, stream>>>(keys, vb_bf, cl_bf);
    k_main<<<4096, 256, 0, stream>>>(q_bf, vb_bf, E_bf, cl_bf, out);
}

// Round 4
// 344.883 us; speedup vs baseline: 3.4923x; 1.4734x over previous
//
#include <hip/hip_runtime.h>
#include <math.h>

// LambdaLayer round 4: MFMA projection GEMM (M=144, N=32768, K=256).
// b=32 d=256 n=m=1024 k=16 h=4 v=64.
// k_projm: A-op = Wb[144][256] bf16 (L2-hot), B-op = x rows (f32->bf16 in-reg),
//          no LDS; 72 MFMAs/wave; f32 stores into keys/vals/qrs (unchanged layouts).
// k_main unchanged from round 3 (bf16 MFMA, A-step/B-step + content virtual K-step).

#define BB 32
#define DD 256
#define NPOS 1024
#define KDIM 16
#define HH 4
#define VV 64
#define F_EPS 1e-5f

#define NBLK 8
#define TMM 64

typedef __attribute__((ext_vector_type(8))) short short8;   // 8 bf16 (4 VGPR)
typedef __attribute__((ext_vector_type(4))) float f32x4;
typedef unsigned short ushort_t;
typedef unsigned int uint_t;

typedef __attribute__((address_space(1))) const uint_t g32_t;
typedef __attribute__((address_space(3))) uint_t l32_t;

__device__ __forceinline__ void gload16(const void* g, void* l) {
    __builtin_amdgcn_global_load_lds((g32_t*)g, (l32_t*)l, 16, 0, 0);
}

__device__ __forceinline__ uint_t bfpack(float x, float y) {   // 2 f32 -> packed bf16 pair (RNE)
    uint_t ux = __float_as_uint(x), uy = __float_as_uint(y);
    ux = (ux + 0x7FFFu + ((ux >> 16) & 1u)) >> 16;
    uy = (uy + 0x7FFFu + ((uy >> 16) & 1u)) >> 16;
    return ux | (uy << 16);
}
__device__ __forceinline__ ushort_t f2bf(float x) {
    uint_t u = __float_as_uint(x);
    return (ushort_t)((u + 0x7FFFu + ((u >> 16) & 1u)) >> 16);
}
__device__ __forceinline__ float bflo(uint_t u) { return __uint_as_float(u << 16); }
__device__ __forceinline__ float bfhi(uint_t u) { return __uint_as_float(u & 0xFFFF0000u); }

// ---------------- W concat + cvt: rows [Wk(16); Wv(64); Wq(64)] -> Wb[144][256] bf16
// grid 18, block 256 (each thread 8 elems).
__global__ void k_wcvt(const float* __restrict__ Wq, const float* __restrict__ Wk,
                       const float* __restrict__ Wv, ushort_t* __restrict__ Wb) {
    int i = blockIdx.x*256 + threadIdx.x;
    int fi = i*8;
    int row = fi >> 8, col = fi & 255;
    const float* src;
    if (row < 16)      src = Wk + row*DD + col;
    else if (row < 80) src = Wv + (row-16)*DD + col;
    else               src = Wq + (row-80)*DD + col;
    float4 a = ((const float4*)src)[0], c = ((const float4*)src)[1];
    uint4 o;
    o.x = bfpack(a.x, a.y); o.y = bfpack(a.z, a.w);
    o.z = bfpack(c.x, c.y); o.w = bfpack(c.z, c.w);
    *(uint4*)(Wb + fi) = o;
}

// ---------------- K1: MFMA projection GEMM ----------------
// grid (32 b, 16 ntiles), block 256 = 4 waves; wave owns n-frag of 16, all 144 channels.
__global__ __launch_bounds__(256) void k_projm(
        const float* __restrict__ x, const ushort_t* __restrict__ Wb,
        float* __restrict__ keys, float* __restrict__ vals, float* __restrict__ qrs) {
    const int b = blockIdx.x, nt = blockIdx.y;
    const int w = threadIdx.x >> 6, lane = threadIdx.x & 63;
    const int l15 = lane & 15, l4 = lane >> 4;
    const int n = nt*64 + w*16 + l15;

    // preload this lane's 8 x-chunks (8 f32 each, d = ks*32 + l4*8)
    const float* xr = x + ((size_t)b*NPOS + n)*DD + l4*8;
    float4 xa[8][2];
    #pragma unroll
    for (int ks = 0; ks < 8; ++ks) {
        xa[ks][0] = *(const float4*)(xr + ks*32);
        xa[ks][1] = *(const float4*)(xr + ks*32 + 4);
    }

    f32x4 acc[9];
    #pragma unroll
    for (int m = 0; m < 9; ++m) acc[m] = (f32x4){0.f,0.f,0.f,0.f};

    const ushort_t* wp = Wb + (size_t)l15*DD + l4*8;
    #pragma unroll
    for (int ks = 0; ks < 8; ++ks) {
        union { uint_t u[4]; short8 s8; } bu;
        bu.u[0] = bfpack(xa[ks][0].x, xa[ks][0].y);
        bu.u[1] = bfpack(xa[ks][0].z, xa[ks][0].w);
        bu.u[2] = bfpack(xa[ks][1].x, xa[ks][1].y);
        bu.u[3] = bfpack(xa[ks][1].z, xa[ks][1].w);
        #pragma unroll
        for (int m = 0; m < 9; ++m) {
            short8 wf = *(const short8*)(wp + (size_t)m*16*DD + ks*32);
            acc[m] = __builtin_amdgcn_mfma_f32_16x16x32_bf16(wf, bu.s8, acc[m], 0, 0, 0);
        }
    }

    // stores: c = m*16 + l4*4 + i, col n; frag-aligned dest boundaries (16, 80)
    #pragma unroll
    for (int m = 0; m < 9; ++m) {
        float* dst;
        int c0 = m*16 + l4*4;
        if (m == 0)      dst = keys + (size_t)b*KDIM*NPOS + (size_t)c0*NPOS;
        else if (m < 5)  dst = vals + (size_t)b*VV*NPOS   + (size_t)(c0-16)*NPOS;
        else             dst = qrs  + (size_t)b*VV*NPOS   + (size_t)(c0-80)*NPOS;
        #pragma unroll
        for (int i = 0; i < 4; ++i)
            dst[(size_t)i*NPOS + n] = acc[m][i];
    }
}

__global__ void k_zero(float* __restrict__ p, int nfl) {
    int i = blockIdx.x * 256 + threadIdx.x;
    if (i < nfl) p[i] = 0.f;
}

// ---------------- E f32 -> bf16 ----------------
__global__ void k_ecvt(const float* __restrict__ E, ushort_t* __restrict__ Eb) {
    size_t i = (size_t)blockIdx.x * 256 + threadIdx.x;   // x8 elems
    const float4* s = (const float4*)(E + i*8);
    float4 a = s[0], c = s[1];
    uint4 o;
    o.x = bfpack(a.x, a.y); o.y = bfpack(a.z, a.w);
    o.z = bfpack(c.x, c.y); o.w = bfpack(c.z, c.w);
    *(uint4*)(Eb + i*8) = o;
}

// ---------------- softmax ----------------
__global__ void k_softmax(float* __restrict__ keys) {
    const int wid  = (blockIdx.x * 256 + threadIdx.x) >> 6;
    const int lane = threadIdx.x & 63;
    float* row = keys + (size_t)wid * NPOS;
    float v[16];
    float mx = -1e30f;
    #pragma unroll
    for (int j = 0; j < 16; ++j) { v[j] = row[lane + 64*j]; mx = fmaxf(mx, v[j]); }
    #pragma unroll
    for (int off = 32; off >= 1; off >>= 1) mx = fmaxf(mx, __shfl_xor(mx, off));
    float s = 0.f;
    #pragma unroll
    for (int j = 0; j < 16; ++j) { v[j] = __expf(v[j] - mx); s += v[j]; }
    #pragma unroll
    for (int off = 32; off >= 1; off >>= 1) s += __shfl_xor(s, off);
    float inv = 1.f / s;
    #pragma unroll
    for (int j = 0; j < 16; ++j) row[lane + 64*j] = v[j] * inv;
}

// ---------------- value BN stats ----------------
__global__ void k_vstats(const float* __restrict__ vals, float* __restrict__ sv) {
    const int g = blockIdx.x, t = threadIdx.x;
    float s[4] = {0,0,0,0}, q[4] = {0,0,0,0};
    for (int r = g*32; r < g*32 + 32; ++r) {
        const float* row = vals + (size_t)r * NPOS;
        #pragma unroll
        for (int j = 0; j < 4; ++j) { float x = row[t + 256*j]; s[j] += x; q[j] += x*x; }
    }
    #pragma unroll
    for (int j = 0; j < 4; ++j) {
        atomicAdd(&sv[t + 256*j], s[j]);
        atomicAdd(&sv[1024 + t + 256*j], q[j]);
    }
}

__global__ void k_vfinal(float* __restrict__ sv, const float* __restrict__ gv,
                         const float* __restrict__ bv) {
    int m = blockIdx.x*256 + threadIdx.x;
    float mean = sv[m] * (1.f/2048.f);
    float var  = sv[1024+m] * (1.f/2048.f) - mean*mean;
    float sc = rsqrtf(var + F_EPS) * gv[m];
    sv[m] = sc;
    sv[1024+m] = bv[m] - mean*sc;
}

// ---------------- BN-apply + cvt: vals f32 -> vb_bf16 [b][v][m] ----------------
__global__ void k_vcvt(const float* __restrict__ vals, const float* __restrict__ sv,
                       ushort_t* __restrict__ vb) {
    int i = blockIdx.x*256 + threadIdx.x;       // x8 elems
    int m0 = (i & 127) * 8;
    const float4* src = (const float4*)(vals + (size_t)i*8);
    float4 a = src[0], c = src[1];
    float4 s0 = *(const float4*)(sv + m0),        s1 = *(const float4*)(sv + m0 + 4);
    float4 h0 = *(const float4*)(sv + 1024 + m0), h1 = *(const float4*)(sv + 1024 + m0 + 4);
    a.x = a.x*s0.x + h0.x; a.y = a.y*s0.y + h0.y; a.z = a.z*s0.z + h0.z; a.w = a.w*s0.w + h0.w;
    c.x = c.x*s1.x + h1.x; c.y = c.y*s1.y + h1.y; c.z = c.z*s1.z + h1.z; c.w = c.w*s1.w + h1.w;
    uint4 o;
    o.x = bfpack(a.x, a.y); o.y = bfpack(a.z, a.w);
    o.z = bfpack(c.x, c.y); o.w = bfpack(c.z, c.w);
    *(uint4*)(vb + (size_t)i*8) = o;
}

// ---------------- query BN stats ----------------
__global__ void k_qstats(const float* __restrict__ qrs, float* __restrict__ sq) {
    const int kd = blockIdx.x >> 3, sub = blockIdx.x & 7;
    float s = 0.f, ss = 0.f;
    for (int b = sub*4; b < sub*4 + 4; ++b)
        for (int h = 0; h < HH; ++h) {
            const float* row = qrs + ((size_t)(b*KDIM*HH) + kd*4 + h) * NPOS;
            #pragma unroll
            for (int j = 0; j < 4; ++j) { float x = row[threadIdx.x + 256*j]; s += x; ss += x*x; }
        }
    #pragma unroll
    for (int off = 32; off >= 1; off >>= 1) { s += __shfl_xor(s, off); ss += __shfl_xor(ss, off); }
    __shared__ float red[8];
    int w = threadIdx.x >> 6, lane = threadIdx.x & 63;
    if (lane == 0) { red[w] = s; red[4+w] = ss; }
    __syncthreads();
    if (threadIdx.x == 0) atomicAdd(&sq[kd],    red[0]+red[1]+red[2]+red[3]);
    if (threadIdx.x == 1) atomicAdd(&sq[16+kd], red[4]+red[5]+red[6]+red[7]);
}

__global__ void k_qfinal(float* __restrict__ sq, const float* __restrict__ gq,
                         const float* __restrict__ bq) {
    int kd = threadIdx.x;
    const float inv = 1.f / 131072.f;
    float mean = sq[kd] * inv;
    float var  = sq[16+kd] * inv - mean*mean;
    float sc = rsqrtf(var + F_EPS) * gq[kd];
    sq[kd] = sc;
    sq[16+kd] = bq[kd] - mean*sc;
}

// ---------------- BN-apply + transpose: qrs[b][kd*4+h][n] -> q_bf16[b][n*4+h][32k] ---
__global__ void k_qT(const float* __restrict__ qrs, const float* __restrict__ sq,
                     ushort_t* __restrict__ qb) {
    __shared__ float tile[64][68];
    const int b = blockIdx.x >> 4, n0 = (blockIdx.x & 15) * 64;
    const int t = threadIdx.x;
    {
        int c = t >> 2, j0 = t & 3;
        const float4* src = (const float4*)(qrs + ((size_t)b*64 + c)*NPOS + n0);
        #pragma unroll
        for (int i = 0; i < 4; ++i) {
            float4 v = src[j0 + i*4];
            *(float4*)&tile[c][(j0 + i*4)*4] = v;
        }
    }
    __syncthreads();
    int n_l = t >> 2, h = t & 3;
    float q16[16];
    #pragma unroll
    for (int kd = 0; kd < 16; ++kd)
        q16[kd] = tile[kd*4 + h][n_l] * sq[kd] + sq[16 + kd];
    uint4 lo, hi, z;
    lo.x = bfpack(q16[0], q16[1]);  lo.y = bfpack(q16[2], q16[3]);
    lo.z = bfpack(q16[4], q16[5]);  lo.w = bfpack(q16[6], q16[7]);
    hi.x = bfpack(q16[8], q16[9]);  hi.y = bfpack(q16[10], q16[11]);
    hi.z = bfpack(q16[12], q16[13]); hi.w = bfpack(q16[14], q16[15]);
    z.x = z.y = z.z = z.w = 0u;
    ushort_t* dst = qb + (size_t)b*131072 + (size_t)((n0 + n_l)*4 + h)*32;
    *(uint4*)(dst)      = lo;
    *(uint4*)(dst + 8)  = hi;
    *(uint4*)(dst + 16) = z;
    *(uint4*)(dst + 24) = z;
}

// ---------------- content lambda -> cl_bf16[b][v][16kd] ----------------
__global__ void k_cl(const float* __restrict__ sk, const ushort_t* __restrict__ vb,
                     ushort_t* __restrict__ clb) {
    const int b = blockIdx.x >> 4, kd = blockIdx.x & 15;
    __shared__ float skl[NPOS];
    __shared__ float red[256];
    const int t = threadIdx.x;
    const float* srow = sk + ((size_t)b*KDIM + kd) * NPOS;
    #pragma unroll
    for (int j = 0; j < 4; ++j) skl[t + 256*j] = srow[t + 256*j];
    __syncthreads();
    const int v = t >> 2, q = t & 3;
    const uint4* v4 = (const uint4*)(vb + ((size_t)b*VV + v) * NPOS + q*256);
    const float4* s4 = (const float4*)(skl + q*256);
    float s = 0.f;
    #pragma unroll 8
    for (int m8 = 0; m8 < 32; ++m8) {
        uint4 wv = v4[m8];
        float4 sa = s4[m8*2], sb = s4[m8*2+1];
        s += sa.x*bflo(wv.x) + sa.y*bfhi(wv.x) + sa.z*bflo(wv.y) + sa.w*bfhi(wv.y)
           + sb.x*bflo(wv.z) + sb.y*bfhi(wv.z) + sb.z*bflo(wv.w) + sb.w*bfhi(wv.w);
    }
    red[t] = s;
    __syncthreads();
    if (q == 0) {
        float r = red[t] + red[t+1] + red[t+2] + red[t+3];
        clb[((size_t)b*VV + v)*16 + kd] = f2bf(r);
    }
}

// ---------------- K4: MFMA main kernel (unchanged) ----------------
__global__ __launch_bounds__(256) void k_main(
        const ushort_t* __restrict__ qb, const ushort_t* __restrict__ vb,
        const ushort_t* __restrict__ Eb, const ushort_t* __restrict__ clb,
        float* __restrict__ out) {
    __shared__ ushort_t E_lds[2][NBLK][TMM][16];   // 32 KB, linear (DMA)
    __shared__ ushort_t vb_lds[2][VV][TMM];        // 16 KB, XOR-swizzled
    __shared__ ushort_t A_lds[32][TMM];            // 4 KB,  XOR-swizzled

    const int wg  = blockIdx.x;
    const int b   = (wg >> 3) & 31;
    const int g   = (wg & 7) * 16 + (wg >> 8);     // XCD-resident E tiles
    const int n0  = g * NBLK;
    const int t   = threadIdx.x;
    const int w   = t >> 6, lane = t & 63;
    const int l15 = lane & 15, l4 = lane >> 4;

    char* Ab = (char*)&A_lds[0][0];

    const int mw = w & 1, vf0 = (w >> 1) * 2;

    short8 qf[2];
    #pragma unroll
    for (int j = 0; j < 2; ++j) {
        const ushort_t* qp = qb + ((size_t)b*131072)
                           + (size_t)((n0 + w*2 + j)*4 + l15)*32 + l4*8;
        qf[j] = *(const short8*)qp;
    }

    const ushort_t* vb_b = vb + (size_t)b*VV*NPOS;

    #define STAGE(mt, bufi) do {                                                  \
        const int m0_ = (mt) * TMM;                                               \
        _Pragma("unroll")                                                         \
        for (int qq = 0; qq < 4; ++qq) {                                          \
            int flat = w*4 + qq, nn_ = flat >> 1, half_ = flat & 1;               \
            const ushort_t* src = Eb + ((size_t)(n0+nn_)*NPOS + m0_)*16           \
                                   + half_*512 + lane*8;                          \
            gload16(src, &E_lds[bufi][nn_][half_*32][0]);                         \
        }                                                                         \
        _Pragma("unroll")                                                         \
        for (int qq = 0; qq < 2; ++qq) {                                          \
            int slot = (w*2 + qq)*64 + lane;                                      \
            int v_ = slot >> 3, cs_ = slot & 7, c_ = cs_ ^ (v_ & 7);              \
            const ushort_t* src = vb_b + (size_t)v_*NPOS + m0_ + c_*8;            \
            gload16(src, (char*)&vb_lds[bufi][0][0] + (w*2 + qq)*1024);           \
        }                                                                         \
    } while (0)

    STAGE(0, 0);
    asm volatile("s_waitcnt vmcnt(0)" ::: "memory");
    __syncthreads();

    f32x4 acc[2];
    acc[0] = (f32x4){0.f,0.f,0.f,0.f};
    acc[1] = (f32x4){0.f,0.f,0.f,0.f};

    int buf = 0;
    for (int mt = 0; mt < NPOS/TMM; ++mt) {
        if (mt < NPOS/TMM - 1) STAGE(mt + 1, buf ^ 1);

        f32x4 aacc[8];
        #pragma unroll
        for (int j = 0; j < 2; ++j) {
            #pragma unroll
            for (int mf = 0; mf < 4; ++mf) {
                short8 e = *(const short8*)&E_lds[buf][w*2 + j][mf*16 + l15][(l4 & 1)*8];
                aacc[j*4 + mf] = __builtin_amdgcn_mfma_f32_16x16x32_bf16(
                    e, qf[j], (f32x4){0.f,0.f,0.f,0.f}, 0, 0, 0);
            }
        }
        __syncthreads();

        if (l15 < 4) {
            #pragma unroll
            for (int j = 0; j < 2; ++j) {
                int arow = (w*2 + j)*4 + l15;
                int sw = (arow & 7) << 4;
                #pragma unroll
                for (int mf = 0; mf < 4; ++mf) {
                    f32x4 a = aacc[j*4 + mf];
                    int byte = (arow*128 + mf*32 + l4*8) ^ sw;
                    *(uint2*)(Ab + byte) = make_uint2(bfpack(a[0], a[1]), bfpack(a[2], a[3]));
                }
            }
        }
        __syncthreads();

        #pragma unroll
        for (int s = 0; s < 2; ++s) {
            int arow = mw*16 + l15;
            int abyte = (arow*128 + s*64 + l4*16) ^ ((arow & 7) << 4);
            short8 af = *(const short8*)(Ab + abyte);
            #pragma unroll
            for (int nf = 0; nf < 2; ++nf) {
                int v_ = (vf0 + nf)*16 + l15;
                int vbyte = (v_*128 + (s*4 + l4)*16) ^ ((v_ & 7) << 4);
                short8 bfr = *(const short8*)((char*)&vb_lds[buf][0][0] + vbyte);
                acc[nf] = __builtin_amdgcn_mfma_f32_16x16x32_bf16(af, bfr, acc[nf], 0, 0, 0);
            }
        }

        asm volatile("s_waitcnt vmcnt(0)" ::: "memory");
        __syncthreads();
        buf ^= 1;
    }

    {
        const ushort_t* qa = qb + (size_t)b*131072
                           + (size_t)(n0*4 + mw*16 + l15)*32 + l4*8;
        short8 aq = *(const short8*)qa;
        #pragma unroll
        for (int nf = 0; nf < 2; ++nf) {
            const ushort_t* cb = clb + ((size_t)b*VV + (vf0 + nf)*16 + l15)*16 + l4*8;
            short8 bq = *(const short8*)cb;
            acc[nf] = __builtin_amdgcn_mfma_f32_16x16x32_bf16(aq, bq, acc[nf], 0, 0, 0);
        }
    }

    #pragma unroll
    for (int nf = 0; nf < 2; ++nf) {
        int v_ = (vf0 + nf)*16 + l15;
        int r0 = mw*16 + l4*4;
        int nn = r0 >> 2;
        #pragma unroll
        for (int i = 0; i < 4; ++i) {
            out[(((size_t)b*HH + i)*VV + v_)*NPOS + n0 + nn] = acc[nf][i];
        }
    }
    #undef STAGE
}

// ---------------- launch -------------------
extern "C" void kernel_launch(void* const* d_in, const int* in_sizes, int n_in,
                              void* d_out, int out_size, void* d_ws, size_t ws_size,
                              hipStream_t stream) {
    const float* x  = (const float*)d_in[0];
    const float* Wq = (const float*)d_in[1];
    const float* Wk = (const float*)d_in[2];
    const float* Wv = (const float*)d_in[3];
    const float* E  = (const float*)d_in[4];
    const float* gv = (const float*)d_in[5];
    const float* bv = (const float*)d_in[6];
    const float* gq = (const float*)d_in[7];
    const float* bq = (const float*)d_in[8];
    float* out = (float*)d_out;

    float* ws   = (float*)d_ws;
    float* keys = ws;                          // 524288 f32
    float* vals = keys + 524288;               // 2097152 f32
    float* qrs  = vals + 2097152;              // 2097152 f32
    float* sv   = qrs  + 2097152;              // 2048
    float* sq   = sv   + 2048;                 // 32
    ushort_t* cl_bf = (ushort_t*)(sq + 32);    // 32832 u16
    ushort_t* q_bf  = cl_bf + 32832;           // 4196352 u16
    ushort_t* vb_bf = q_bf  + 4196352;         // 2097152 u16
    ushort_t* E_bf  = vb_bf + 2097152;         // 16777216 u16
    ushort_t* W_bf  = E_bf  + 16777216;        // 36864 u16
    // total ~65.3 MB of d_ws

    k_zero<<<9, 256, 0, stream>>>(sv, 2048 + 32);
    k_wcvt<<<18, 256, 0, stream>>>(Wq, Wk, Wv, W_bf);
    k_projm<<<dim3(BB, 16), 256, 0, stream>>>(x, W_bf, keys, vals, qrs);
    k_ecvt<<<8192, 256, 0, stream>>>(E, E_bf);
    k_softmax<<<128, 256, 0, stream>>>(keys);
    k_vstats<<<64, 256, 0, stream>>>(vals, sv);
    k_vfinal<<<4, 256, 0, stream>>>(sv, gv, bv);
    k_vcvt<<<1024, 256, 0, stream>>>(vals, sv, vb_bf);
    k_qstats<<<128, 256, 0, stream>>>(qrs, sq);
    k_qfinal<<<1, 16, 0, stream>>>(sq, gq, bq);
    k_qT<<<512, 256, 0, stream>>>(qrs, sq, q_bf);
    k_cl<<<512, 256, 0, stream>>>(keys, vb_bf, cl_bf);
    k_main<<<4096, 256, 0, stream>>>(q_bf, vb_bf, E_bf, cl_bf, out);
}

// Round 5
// 337.887 us; speedup vs baseline: 3.5646x; 1.0207x over previous
//
#include <hip/hip_runtime.h>
#include <math.h>

// LambdaLayer round 5: k_main rescheduled — 2 raw barriers/iter, counted-latency
// staging (drain covers stage issued one full iter earlier), pointer-increment
// staging addresses, setprio around MFMA clusters. All other kernels unchanged.

#define BB 32
#define DD 256
#define NPOS 1024
#define KDIM 16
#define HH 4
#define VV 64
#define F_EPS 1e-5f

#define NBLK 8
#define TMM 64

typedef __attribute__((ext_vector_type(8))) short short8;   // 8 bf16 (4 VGPR)
typedef __attribute__((ext_vector_type(4))) float f32x4;
typedef unsigned short ushort_t;
typedef unsigned int uint_t;

typedef __attribute__((address_space(1))) const uint_t g32_t;
typedef __attribute__((address_space(3))) uint_t l32_t;

__device__ __forceinline__ void gload16(const void* g, void* l) {
    __builtin_amdgcn_global_load_lds((g32_t*)g, (l32_t*)l, 16, 0, 0);
}

__device__ __forceinline__ uint_t bfpack(float x, float y) {   // 2 f32 -> packed bf16 pair (RNE)
    uint_t ux = __float_as_uint(x), uy = __float_as_uint(y);
    ux = (ux + 0x7FFFu + ((ux >> 16) & 1u)) >> 16;
    uy = (uy + 0x7FFFu + ((uy >> 16) & 1u)) >> 16;
    return ux | (uy << 16);
}
__device__ __forceinline__ ushort_t f2bf(float x) {
    uint_t u = __float_as_uint(x);
    return (ushort_t)((u + 0x7FFFu + ((u >> 16) & 1u)) >> 16);
}
__device__ __forceinline__ float bflo(uint_t u) { return __uint_as_float(u << 16); }
__device__ __forceinline__ float bfhi(uint_t u) { return __uint_as_float(u & 0xFFFF0000u); }

// ---------------- W concat + cvt ----------------
__global__ void k_wcvt(const float* __restrict__ Wq, const float* __restrict__ Wk,
                       const float* __restrict__ Wv, ushort_t* __restrict__ Wb) {
    int i = blockIdx.x*256 + threadIdx.x;
    int fi = i*8;
    int row = fi >> 8, col = fi & 255;
    const float* src;
    if (row < 16)      src = Wk + row*DD + col;
    else if (row < 80) src = Wv + (row-16)*DD + col;
    else               src = Wq + (row-80)*DD + col;
    float4 a = ((const float4*)src)[0], c = ((const float4*)src)[1];
    uint4 o;
    o.x = bfpack(a.x, a.y); o.y = bfpack(a.z, a.w);
    o.z = bfpack(c.x, c.y); o.w = bfpack(c.z, c.w);
    *(uint4*)(Wb + fi) = o;
}

// ---------------- K1: MFMA projection GEMM ----------------
__global__ __launch_bounds__(256) void k_projm(
        const float* __restrict__ x, const ushort_t* __restrict__ Wb,
        float* __restrict__ keys, float* __restrict__ vals, float* __restrict__ qrs) {
    const int b = blockIdx.x, nt = blockIdx.y;
    const int w = threadIdx.x >> 6, lane = threadIdx.x & 63;
    const int l15 = lane & 15, l4 = lane >> 4;
    const int n = nt*64 + w*16 + l15;

    const float* xr = x + ((size_t)b*NPOS + n)*DD + l4*8;
    float4 xa[8][2];
    #pragma unroll
    for (int ks = 0; ks < 8; ++ks) {
        xa[ks][0] = *(const float4*)(xr + ks*32);
        xa[ks][1] = *(const float4*)(xr + ks*32 + 4);
    }

    f32x4 acc[9];
    #pragma unroll
    for (int m = 0; m < 9; ++m) acc[m] = (f32x4){0.f,0.f,0.f,0.f};

    const ushort_t* wp = Wb + (size_t)l15*DD + l4*8;
    #pragma unroll
    for (int ks = 0; ks < 8; ++ks) {
        union { uint_t u[4]; short8 s8; } bu;
        bu.u[0] = bfpack(xa[ks][0].x, xa[ks][0].y);
        bu.u[1] = bfpack(xa[ks][0].z, xa[ks][0].w);
        bu.u[2] = bfpack(xa[ks][1].x, xa[ks][1].y);
        bu.u[3] = bfpack(xa[ks][1].z, xa[ks][1].w);
        #pragma unroll
        for (int m = 0; m < 9; ++m) {
            short8 wf = *(const short8*)(wp + (size_t)m*16*DD + ks*32);
            acc[m] = __builtin_amdgcn_mfma_f32_16x16x32_bf16(wf, bu.s8, acc[m], 0, 0, 0);
        }
    }

    #pragma unroll
    for (int m = 0; m < 9; ++m) {
        float* dst;
        int c0 = m*16 + l4*4;
        if (m == 0)      dst = keys + (size_t)b*KDIM*NPOS + (size_t)c0*NPOS;
        else if (m < 5)  dst = vals + (size_t)b*VV*NPOS   + (size_t)(c0-16)*NPOS;
        else             dst = qrs  + (size_t)b*VV*NPOS   + (size_t)(c0-80)*NPOS;
        #pragma unroll
        for (int i = 0; i < 4; ++i)
            dst[(size_t)i*NPOS + n] = acc[m][i];
    }
}

__global__ void k_zero(float* __restrict__ p, int nfl) {
    int i = blockIdx.x * 256 + threadIdx.x;
    if (i < nfl) p[i] = 0.f;
}

// ---------------- E f32 -> bf16 ----------------
__global__ void k_ecvt(const float* __restrict__ E, ushort_t* __restrict__ Eb) {
    size_t i = (size_t)blockIdx.x * 256 + threadIdx.x;
    const float4* s = (const float4*)(E + i*8);
    float4 a = s[0], c = s[1];
    uint4 o;
    o.x = bfpack(a.x, a.y); o.y = bfpack(a.z, a.w);
    o.z = bfpack(c.x, c.y); o.w = bfpack(c.z, c.w);
    *(uint4*)(Eb + i*8) = o;
}

// ---------------- softmax ----------------
__global__ void k_softmax(float* __restrict__ keys) {
    const int wid  = (blockIdx.x * 256 + threadIdx.x) >> 6;
    const int lane = threadIdx.x & 63;
    float* row = keys + (size_t)wid * NPOS;
    float v[16];
    float mx = -1e30f;
    #pragma unroll
    for (int j = 0; j < 16; ++j) { v[j] = row[lane + 64*j]; mx = fmaxf(mx, v[j]); }
    #pragma unroll
    for (int off = 32; off >= 1; off >>= 1) mx = fmaxf(mx, __shfl_xor(mx, off));
    float s = 0.f;
    #pragma unroll
    for (int j = 0; j < 16; ++j) { v[j] = __expf(v[j] - mx); s += v[j]; }
    #pragma unroll
    for (int off = 32; off >= 1; off >>= 1) s += __shfl_xor(s, off);
    float inv = 1.f / s;
    #pragma unroll
    for (int j = 0; j < 16; ++j) row[lane + 64*j] = v[j] * inv;
}

// ---------------- value BN stats ----------------
__global__ void k_vstats(const float* __restrict__ vals, float* __restrict__ sv) {
    const int g = blockIdx.x, t = threadIdx.x;
    float s[4] = {0,0,0,0}, q[4] = {0,0,0,0};
    for (int r = g*32; r < g*32 + 32; ++r) {
        const float* row = vals + (size_t)r * NPOS;
        #pragma unroll
        for (int j = 0; j < 4; ++j) { float x = row[t + 256*j]; s[j] += x; q[j] += x*x; }
    }
    #pragma unroll
    for (int j = 0; j < 4; ++j) {
        atomicAdd(&sv[t + 256*j], s[j]);
        atomicAdd(&sv[1024 + t + 256*j], q[j]);
    }
}

__global__ void k_vfinal(float* __restrict__ sv, const float* __restrict__ gv,
                         const float* __restrict__ bv) {
    int m = blockIdx.x*256 + threadIdx.x;
    float mean = sv[m] * (1.f/2048.f);
    float var  = sv[1024+m] * (1.f/2048.f) - mean*mean;
    float sc = rsqrtf(var + F_EPS) * gv[m];
    sv[m] = sc;
    sv[1024+m] = bv[m] - mean*sc;
}

// ---------------- BN-apply + cvt: vals f32 -> vb_bf16 [b][v][m] ----------------
__global__ void k_vcvt(const float* __restrict__ vals, const float* __restrict__ sv,
                       ushort_t* __restrict__ vb) {
    int i = blockIdx.x*256 + threadIdx.x;
    int m0 = (i & 127) * 8;
    const float4* src = (const float4*)(vals + (size_t)i*8);
    float4 a = src[0], c = src[1];
    float4 s0 = *(const float4*)(sv + m0),        s1 = *(const float4*)(sv + m0 + 4);
    float4 h0 = *(const float4*)(sv + 1024 + m0), h1 = *(const float4*)(sv + 1024 + m0 + 4);
    a.x = a.x*s0.x + h0.x; a.y = a.y*s0.y + h0.y; a.z = a.z*s0.z + h0.z; a.w = a.w*s0.w + h0.w;
    c.x = c.x*s1.x + h1.x; c.y = c.y*s1.y + h1.y; c.z = c.z*s1.z + h1.z; c.w = c.w*s1.w + h1.w;
    uint4 o;
    o.x = bfpack(a.x, a.y); o.y = bfpack(a.z, a.w);
    o.z = bfpack(c.x, c.y); o.w = bfpack(c.z, c.w);
    *(uint4*)(vb + (size_t)i*8) = o;
}

// ---------------- query BN stats ----------------
__global__ void k_qstats(const float* __restrict__ qrs, float* __restrict__ sq) {
    const int kd = blockIdx.x >> 3, sub = blockIdx.x & 7;
    float s = 0.f, ss = 0.f;
    for (int b = sub*4; b < sub*4 + 4; ++b)
        for (int h = 0; h < HH; ++h) {
            const float* row = qrs + ((size_t)(b*KDIM*HH) + kd*4 + h) * NPOS;
            #pragma unroll
            for (int j = 0; j < 4; ++j) { float x = row[threadIdx.x + 256*j]; s += x; ss += x*x; }
        }
    #pragma unroll
    for (int off = 32; off >= 1; off >>= 1) { s += __shfl_xor(s, off); ss += __shfl_xor(ss, off); }
    __shared__ float red[8];
    int w = threadIdx.x >> 6, lane = threadIdx.x & 63;
    if (lane == 0) { red[w] = s; red[4+w] = ss; }
    __syncthreads();
    if (threadIdx.x == 0) atomicAdd(&sq[kd],    red[0]+red[1]+red[2]+red[3]);
    if (threadIdx.x == 1) atomicAdd(&sq[16+kd], red[4]+red[5]+red[6]+red[7]);
}

__global__ void k_qfinal(float* __restrict__ sq, const float* __restrict__ gq,
                         const float* __restrict__ bq) {
    int kd = threadIdx.x;
    const float inv = 1.f / 131072.f;
    float mean = sq[kd] * inv;
    float var  = sq[16+kd] * inv - mean*mean;
    float sc = rsqrtf(var + F_EPS) * gq[kd];
    sq[kd] = sc;
    sq[16+kd] = bq[kd] - mean*sc;
}

// ---------------- BN-apply + transpose: qrs -> q_bf16[b][n*4+h][32k] ----------
__global__ void k_qT(const float* __restrict__ qrs, const float* __restrict__ sq,
                     ushort_t* __restrict__ qb) {
    __shared__ float tile[64][68];
    const int b = blockIdx.x >> 4, n0 = (blockIdx.x & 15) * 64;
    const int t = threadIdx.x;
    {
        int c = t >> 2, j0 = t & 3;
        const float4* src = (const float4*)(qrs + ((size_t)b*64 + c)*NPOS + n0);
        #pragma unroll
        for (int i = 0; i < 4; ++i) {
            float4 v = src[j0 + i*4];
            *(float4*)&tile[c][(j0 + i*4)*4] = v;
        }
    }
    __syncthreads();
    int n_l = t >> 2, h = t & 3;
    float q16[16];
    #pragma unroll
    for (int kd = 0; kd < 16; ++kd)
        q16[kd] = tile[kd*4 + h][n_l] * sq[kd] + sq[16 + kd];
    uint4 lo, hi, z;
    lo.x = bfpack(q16[0], q16[1]);  lo.y = bfpack(q16[2], q16[3]);
    lo.z = bfpack(q16[4], q16[5]);  lo.w = bfpack(q16[6], q16[7]);
    hi.x = bfpack(q16[8], q16[9]);  hi.y = bfpack(q16[10], q16[11]);
    hi.z = bfpack(q16[12], q16[13]); hi.w = bfpack(q16[14], q16[15]);
    z.x = z.y = z.z = z.w = 0u;
    ushort_t* dst = qb + (size_t)b*131072 + (size_t)((n0 + n_l)*4 + h)*32;
    *(uint4*)(dst)      = lo;
    *(uint4*)(dst + 8)  = hi;
    *(uint4*)(dst + 16) = z;
    *(uint4*)(dst + 24) = z;
}

// ---------------- content lambda -> cl_bf16[b][v][16kd] ----------------
__global__ void k_cl(const float* __restrict__ sk, const ushort_t* __restrict__ vb,
                     ushort_t* __restrict__ clb) {
    const int b = blockIdx.x >> 4, kd = blockIdx.x & 15;
    __shared__ float skl[NPOS];
    __shared__ float red[256];
    const int t = threadIdx.x;
    const float* srow = sk + ((size_t)b*KDIM + kd) * NPOS;
    #pragma unroll
    for (int j = 0; j < 4; ++j) skl[t + 256*j] = srow[t + 256*j];
    __syncthreads();
    const int v = t >> 2, q = t & 3;
    const uint4* v4 = (const uint4*)(vb + ((size_t)b*VV + v) * NPOS + q*256);
    const float4* s4 = (const float4*)(skl + q*256);
    float s = 0.f;
    #pragma unroll 8
    for (int m8 = 0; m8 < 32; ++m8) {
        uint4 wv = v4[m8];
        float4 sa = s4[m8*2], sb = s4[m8*2+1];
        s += sa.x*bflo(wv.x) + sa.y*bfhi(wv.x) + sa.z*bflo(wv.y) + sa.w*bfhi(wv.y)
           + sb.x*bflo(wv.z) + sb.y*bfhi(wv.z) + sb.z*bflo(wv.w) + sb.w*bfhi(wv.w);
    }
    red[t] = s;
    __syncthreads();
    if (q == 0) {
        float r = red[t] + red[t+1] + red[t+2] + red[t+3];
        clb[((size_t)b*VV + v)*16 + kd] = f2bf(r);
    }
}

// ---------------- K4: MFMA main kernel (rescheduled) ----------------
// grid 4096; block 256 = 4 waves. Per iter: vmcnt(0)[covers stage issued a full
// iter ago] + barrier -> stage(next) -> A-MFMA -> A-write -> lgkm+barrier -> B-MFMA.
__global__ __launch_bounds__(256) void k_main(
        const ushort_t* __restrict__ qb, const ushort_t* __restrict__ vb,
        const ushort_t* __restrict__ Eb, const ushort_t* __restrict__ clb,
        float* __restrict__ out) {
    __shared__ ushort_t E_lds[2][NBLK][TMM][16];   // 32 KB, linear (DMA)
    __shared__ ushort_t vb_lds[2][VV][TMM];        // 16 KB, XOR-swizzled
    __shared__ ushort_t A_lds[32][TMM];            // 4 KB,  XOR-swizzled

    const int wg  = blockIdx.x;
    const int b   = (wg >> 3) & 31;
    const int g   = (wg & 7) * 16 + (wg >> 8);     // XCD-resident E tiles
    const int n0  = g * NBLK;
    const int t   = threadIdx.x;
    const int w   = t >> 6, lane = t & 63;
    const int l15 = lane & 15, l4 = lane >> 4;

    char* Ab    = (char*)&A_lds[0][0];
    char* Ebase = (char*)&E_lds[0][0][0][0];
    char* Vbase = (char*)&vb_lds[0][0][0];

    const int mw = w & 1, vf0 = (w >> 1) * 2;

    // q fragments (2 global loads; drained by first in-loop vmcnt(0))
    short8 qf[2];
    #pragma unroll
    for (int j = 0; j < 2; ++j) {
        const ushort_t* qp = qb + ((size_t)b*131072)
                           + (size_t)((n0 + w*2 + j)*4 + l15)*32 + l4*8;
        qf[j] = *(const short8*)qp;
    }

    // staging state: pointer-incremented sources, fixed LDS byte offsets
    const ushort_t* vb_b = vb + (size_t)b*VV*NPOS;
    const ushort_t* eSrc[4]; uint_t eOffB[4];
    #pragma unroll
    for (int qq = 0; qq < 4; ++qq) {
        int flat = w*4 + qq, nn_ = flat >> 1, half_ = flat & 1;
        eSrc[qq]  = Eb + ((size_t)(n0+nn_)*NPOS)*16 + half_*512 + lane*8;
        eOffB[qq] = nn_*2048u + half_*1024u;
    }
    const ushort_t* vSrc[2]; uint_t vOffB[2];
    #pragma unroll
    for (int qq = 0; qq < 2; ++qq) {
        int slot = (w*2 + qq)*64 + lane;
        int v_ = slot >> 3, cs_ = slot & 7, c_ = cs_ ^ (v_ & 7);
        vSrc[qq]  = vb_b + (size_t)v_*NPOS + c_*8;
        vOffB[qq] = (w*2 + qq)*1024u;
    }

    #define STAGE2(bufsel) do {                                        \
        _Pragma("unroll")                                              \
        for (int qq = 0; qq < 4; ++qq) {                               \
            gload16(eSrc[qq], Ebase + (bufsel)*16384u + eOffB[qq]);    \
            eSrc[qq] += 1024;                                          \
        }                                                              \
        _Pragma("unroll")                                              \
        for (int qq = 0; qq < 2; ++qq) {                               \
            gload16(vSrc[qq], Vbase + (bufsel)*8192u + vOffB[qq]);     \
            vSrc[qq] += 64;                                            \
        }                                                              \
    } while (0)

    STAGE2(0);

    f32x4 acc[2];
    acc[0] = (f32x4){0.f,0.f,0.f,0.f};
    acc[1] = (f32x4){0.f,0.f,0.f,0.f};

    int buf = 0;
    #pragma unroll 4
    for (int mt = 0; mt < NPOS/TMM; ++mt) {
        // stage(mt) was issued one full iteration ago -> latency covered
        asm volatile("s_waitcnt vmcnt(0)" ::: "memory");
        __builtin_amdgcn_s_barrier();          // staging visible; A_lds & buf^1 free
        asm volatile("" ::: "memory");

        if (mt < NPOS/TMM - 1) STAGE2(buf ^ 1);

        // ---- A-step: 8 MFMAs (2 n x 4 m-frags), read E_lds[buf]
        __builtin_amdgcn_s_setprio(1);
        f32x4 aacc[8];
        #pragma unroll
        for (int j = 0; j < 2; ++j) {
            #pragma unroll
            for (int mf = 0; mf < 4; ++mf) {
                short8 e = *(const short8*)&E_lds[buf][w*2 + j][mf*16 + l15][(l4 & 1)*8];
                aacc[j*4 + mf] = __builtin_amdgcn_mfma_f32_16x16x32_bf16(
                    e, qf[j], (f32x4){0.f,0.f,0.f,0.f}, 0, 0, 0);
            }
        }
        __builtin_amdgcn_s_setprio(0);

        // ---- write A (16 active lanes per frag), swizzled
        if (l15 < 4) {
            #pragma unroll
            for (int j = 0; j < 2; ++j) {
                int arow = (w*2 + j)*4 + l15;
                int sw = (arow & 7) << 4;
                #pragma unroll
                for (int mf = 0; mf < 4; ++mf) {
                    f32x4 a = aacc[j*4 + mf];
                    int byte = (arow*128 + mf*32 + l4*8) ^ sw;
                    *(uint2*)(Ab + byte) = make_uint2(bfpack(a[0], a[1]), bfpack(a[2], a[3]));
                }
            }
        }
        asm volatile("s_waitcnt lgkmcnt(0)" ::: "memory");
        __builtin_amdgcn_s_barrier();          // A visible
        asm volatile("" ::: "memory");

        // ---- B-step: 4 MFMAs
        __builtin_amdgcn_s_setprio(1);
        #pragma unroll
        for (int s = 0; s < 2; ++s) {
            int arow = mw*16 + l15;
            int abyte = (arow*128 + s*64 + l4*16) ^ ((arow & 7) << 4);
            short8 af = *(const short8*)(Ab + abyte);
            #pragma unroll
            for (int nf = 0; nf < 2; ++nf) {
                int v_ = (vf0 + nf)*16 + l15;
                int vbyte = (v_*128 + (s*4 + l4)*16) ^ ((v_ & 7) << 4);
                short8 bfr = *(const short8*)((char*)&vb_lds[buf][0][0] + vbyte);
                acc[nf] = __builtin_amdgcn_mfma_f32_16x16x32_bf16(af, bfr, acc[nf], 0, 0, 0);
            }
        }
        __builtin_amdgcn_s_setprio(0);
        buf ^= 1;
    }

    // ---- virtual K-step: content term
    {
        const ushort_t* qa = qb + (size_t)b*131072
                           + (size_t)(n0*4 + mw*16 + l15)*32 + l4*8;
        short8 aq = *(const short8*)qa;
        #pragma unroll
        for (int nf = 0; nf < 2; ++nf) {
            const ushort_t* cb = clb + ((size_t)b*VV + (vf0 + nf)*16 + l15)*16 + l4*8;
            short8 bq = *(const short8*)cb;
            acc[nf] = __builtin_amdgcn_mfma_f32_16x16x32_bf16(aq, bq, acc[nf], 0, 0, 0);
        }
    }

    // ---- store
    #pragma unroll
    for (int nf = 0; nf < 2; ++nf) {
        int v_ = (vf0 + nf)*16 + l15;
        int r0 = mw*16 + l4*4;
        int nn = r0 >> 2;
        #pragma unroll
        for (int i = 0; i < 4; ++i) {
            out[(((size_t)b*HH + i)*VV + v_)*NPOS + n0 + nn] = acc[nf][i];
        }
    }
    #undef STAGE2
}

// ---------------- launch -------------------
extern "C" void kernel_launch(void* const* d_in, const int* in_sizes, int n_in,
                              void* d_out, int out_size, void* d_ws, size_t ws_size,
                              hipStream_t stream) {
    const float* x  = (const float*)d_in[0];
    const float* Wq = (const float*)d_in[1];
    const float* Wk = (const float*)d_in[2];
    const float* Wv = (const float*)d_in[3];
    const float* E  = (const float*)d_in[4];
    const float* gv = (const float*)d_in[5];
    const float* bv = (const float*)d_in[6];
    const float* gq = (const float*)d_in[7];
    const float* bq = (const float*)d_in[8];
    float* out = (float*)d_out;

    float* ws   = (float*)d_ws;
    float* keys = ws;                          // 524288 f32
    float* vals = keys + 524288;               // 2097152 f32
    float* qrs  = vals + 2097152;              // 2097152 f32
    float* sv   = qrs  + 2097152;              // 2048
    float* sq   = sv   + 2048;                 // 32
    ushort_t* cl_bf = (ushort_t*)(sq + 32);    // 32832 u16
    ushort_t* q_bf  = cl_bf + 32832;           // 4196352 u16
    ushort_t* vb_bf = q_bf  + 4196352;         // 2097152 u16
    ushort_t* E_bf  = vb_bf + 2097152;         // 16777216 u16
    ushort_t* W_bf  = E_bf  + 16777216;        // 36864 u16

    k_zero<<<9, 256, 0, stream>>>(sv, 2048 + 32);
    k_wcvt<<<18, 256, 0, stream>>>(Wq, Wk, Wv, W_bf);
    k_projm<<<dim3(BB, 16), 256, 0, stream>>>(x, W_bf, keys, vals, qrs);
    k_ecvt<<<8192, 256, 0, stream>>>(E, E_bf);
    k_softmax<<<128, 256, 0, stream>>>(keys);
    k_vstats<<<64, 256, 0, stream>>>(vals, sv);
    k_vfinal<<<4, 256, 0, stream>>>(sv, gv, bv);
    k_vcvt<<<1024, 256, 0, stream>>>(vals, sv, vb_bf);
    k_qstats<<<128, 256, 0, stream>>>(qrs, sq);
    k_qfinal<<<1, 16, 0, stream>>>(sq, gq, bq);
    k_qT<<<512, 256, 0, stream>>>(qrs, sq, q_bf);
    k_cl<<<512, 256, 0, stream>>>(keys, vb_bf, cl_bf);
    k_main<<<4096, 256, 0, stream>>>(q_bf, vb_bf, E_bf, cl_bf, out);
}